// Round 16
// baseline (384.032 us; speedup 1.0000x reference)
//
#include <hip/hip_runtime.h>
#include <hip/hip_bf16.h>

typedef __attribute__((ext_vector_type(8))) short short8;
typedef __attribute__((ext_vector_type(4))) float f32x4;

#define B_T 200
#define B_D 128
#define ALD 136   // padded bf16 leading dim for staged x tiles (row = 272 B)

static __device__ __forceinline__ short f2bf(float f) {
  // round-to-nearest-even f32 -> bf16 (inputs are finite)
  unsigned u = __builtin_bit_cast(unsigned, f);
  u += 0x7fffu + ((u >> 16) & 1u);
  return (short)(u >> 16);
}
static __device__ __forceinline__ short8 cvt8(f32x4 a, f32x4 b) {
  short8 t;
  t[0] = f2bf(a[0]); t[1] = f2bf(a[1]); t[2] = f2bf(a[2]); t[3] = f2bf(a[3]);
  t[4] = f2bf(b[0]); t[5] = f2bf(b[1]); t[6] = f2bf(b[2]); t[7] = f2bf(b[3]);
  return t;
}

// 256 threads / 4 waves. Wb lives in REGISTERS (each wave owns nt=2w,2w+1 ->
// 32 VGPRs); x tiles staged in LDS (21 KB total) -> 5 blocks/CU at
// waves_per_eu(5,5) (102-reg cap, est demand ~95).
__global__ __launch_bounds__(256)
__attribute__((amdgpu_waves_per_eu(5, 5)))
void ta_fused(const float* __restrict__ x,      // [B,T,D]
              const float* __restrict__ cand,   // [B,D]
              const void*  __restrict__ maskp,  // [B,T] int32 or 1-byte bool
              const float* __restrict__ W1,     // [384,128]
              const float* __restrict__ b1,     // [128]
              const float* __restrict__ ap,     // [1]
              const float* __restrict__ W2,     // [128]
              const float* __restrict__ b2p,    // [1] (unused: softmax shift-invariant)
              float* __restrict__ out)          // [B,D]
{
  __shared__ __align__(16) short a_lds[3][16 * ALD];  // 12.75 KB: x tiles bf16
  __shared__ float sp[4][208];                        // per-wave score partials
  __shared__ float scores[208];
  __shared__ float part[8][B_D];                      // phase-C partials
  __shared__ float red[8];

  const int b    = blockIdx.x;
  const int tid  = threadIdx.x;
  const int lane = tid & 63;
  const int wv   = tid >> 6;      // 0..3
  const int l15  = lane & 15;
  const int g    = lane >> 4;     // 0..3

  // ---- mask dtype probe (same 512B on every wave -> block-consistent)
  int flag1b;
  {
    const unsigned char* mb = (const unsigned char*)maskp;
    unsigned long long v8 = *(const unsigned long long*)(mb + lane * 8);
    flag1b = __any((v8 & 0xFFFFFF00FFFFFF00ull) != 0ull);
  }
  bool mk = false;
  if (tid < B_T) {
    if (flag1b) mk = ((const unsigned char*)maskp)[(size_t)b * B_T + tid] != 0;
    else        mk = ((const int*)maskp)[(size_t)b * B_T + tid] != 0;
  }

  // ---- stage tiles 0 and 1 (loads issued before the Wb build -> overlap)
#define STAGE(MT, BUF) do {                                                   \
    int srow_ = (MT) * 16 + (tid >> 4);                                       \
    if (srow_ > B_T - 1) srow_ = B_T - 1;                                     \
    const float* xp_ = x + ((size_t)b * B_T + srow_) * B_D + (tid & 15) * 8;  \
    f32x4 v0_ = *(const f32x4*)xp_;                                           \
    f32x4 v1_ = *(const f32x4*)(xp_ + 4);                                     \
    *(short8*)&a_lds[BUF][(tid >> 4) * ALD + (tid & 15) * 8] = cvt8(v0_, v1_);\
  } while (0)

  STAGE(0, 0);
  STAGE(1, 1);

  // ---- phase 1 (register-resident, no LDS, no barrier):
  // B-frags for nt=2wv (j0=32wv+l15) and nt=2wv+1 (j1=j0+16):
  // B0[ks] elem e = bf16(W1a[k][j] + c[k]*W1c[k][j]), k = ks*32+g*8+e.
  const float* cb = cand + (size_t)b * B_D;
  const int j0 = wv * 32 + l15, j1 = j0 + 16;
  short8 B0[4], B1[4];
  #pragma unroll
  for (int ks = 0; ks < 4; ++ks) {
    short8 t0, t1;
    #pragma unroll
    for (int e = 0; e < 8; ++e) {
      const int k = ks * 32 + g * 8 + e;
      float c = cb[k];
      t0[e] = f2bf(fmaf(c, W1[(size_t)(256 + k) * B_D + j0], W1[(size_t)k * B_D + j0]));
      t1[e] = f2bf(fmaf(c, W1[(size_t)(256 + k) * B_D + j1], W1[(size_t)k * B_D + j1]));
    }
    B0[ks] = t0; B1[ks] = t1;
  }
  // beta for j0/j1: lane (g) sums k in [g*32,g*32+32), then reduce over g.
  float betaL0, betaL1;
  {
    float s0 = 0.f, s1 = 0.f;
    #pragma unroll 8
    for (int kk = 0; kk < 32; ++kk) {
      const int k = g * 32 + kk;
      float c = cb[k];
      s0 = fmaf(c, W1[(size_t)(B_D + k) * B_D + j0], s0);
      s1 = fmaf(c, W1[(size_t)(B_D + k) * B_D + j1], s1);
    }
    s0 += __shfl_xor(s0, 16, 64); s0 += __shfl_xor(s0, 32, 64);
    s1 += __shfl_xor(s1, 16, 64); s1 += __shfl_xor(s1, 32, 64);
    betaL0 = s0 + b1[j0];
    betaL1 = s1 + b1[j1];
  }
  const float w2L0 = W2[j0], w2L1 = W2[j1];
  const float alpha = ap[0];
  __syncthreads();   // tiles 0,1 staged

  // ---- phase A: 13 tiles, triple-buffered (prefetch distance 2).
  for (int mt = 0; mt < 13; ++mt) {
    const int buf = mt % 3;
    if (mt + 2 < 13) STAGE(mt + 2, (mt + 2) % 3);
    f32x4 acc0 = {0.f, 0.f, 0.f, 0.f}, acc1 = {0.f, 0.f, 0.f, 0.f};
    #pragma unroll
    for (int ks = 0; ks < 4; ++ks) {
      short8 a = *(const short8*)&a_lds[buf][l15 * ALD + ks * 32 + g * 8];
      acc0 = __builtin_amdgcn_mfma_f32_16x16x32_bf16(a, B0[ks], acc0, 0, 0, 0);
      acc1 = __builtin_amdgcn_mfma_f32_16x16x32_bf16(a, B1[ks], acc1, 0, 0, 0);
    }
    // epilogue: PReLU + W2 over this wave's 32 j, reduce over l15
    #pragma unroll
    for (int r = 0; r < 4; ++r) {
      float h0 = acc0[r] + betaL0; h0 = (h0 >= 0.f) ? h0 : alpha * h0;
      float h1 = acc1[r] + betaL1; h1 = (h1 >= 0.f) ? h1 : alpha * h1;
      float v = h0 * w2L0 + h1 * w2L1;
      v += __shfl_xor(v, 1, 16); v += __shfl_xor(v, 2, 16);
      v += __shfl_xor(v, 4, 16); v += __shfl_xor(v, 8, 16);
      if (l15 == 0) sp[wv][mt * 16 + g * 4 + r] = v;   // C row = g*4+r
    }
    __syncthreads();   // releases buf for overwrite; commits staged tile
  }
#undef STAGE

  // ---- phase B: sum wave partials, masked softmax; scores <- UNNORMALIZED e.
  {
    float s = -INFINITY;
    if (tid < B_T && mk) s = (sp[0][tid] + sp[1][tid]) + (sp[2][tid] + sp[3][tid]);
    float v = s;
    #pragma unroll
    for (int m = 32; m >= 1; m >>= 1) v = fmaxf(v, __shfl_xor(v, m, 64));
    if (lane == 0) red[wv] = v;
    __syncthreads();
    float mx = fmaxf(fmaxf(red[0], red[1]), fmaxf(red[2], red[3]));
    float e = (tid < B_T && mk) ? __expf(s - mx) : 0.f;
    float sv = e;
    #pragma unroll
    for (int m = 32; m >= 1; m >>= 1) sv += __shfl_xor(sv, m, 64);
    if (lane == 0) red[4 + wv] = sv;
    if (tid < 208) scores[tid] = e;   // tid in [200,208): e==0
    __syncthreads();
  }

  // ---- phase C: part[p][:] = sum_{t in p-slice} e[t]*x[t,:] (L2/L3-hot).
  {
    const int d4 = (tid & 31) << 2;
    const int p  = tid >> 5;            // 0..7, t in [25p, 25p+25)
    const float* xc = x + ((size_t)b * B_T + p * 25) * B_D + d4;
    f32x4 acc0 = {0.f, 0.f, 0.f, 0.f}, acc1 = {0.f, 0.f, 0.f, 0.f};
    #pragma unroll
    for (int t = 0; t < 24; t += 2) {
      f32x4 xv0 = *(const f32x4*)(xc + (size_t)t * B_D);
      f32x4 xv1 = *(const f32x4*)(xc + (size_t)(t + 1) * B_D);
      float w0 = scores[p * 25 + t];
      float w1 = scores[p * 25 + t + 1];
      acc0[0] = fmaf(w0, xv0[0], acc0[0]); acc1[0] = fmaf(w1, xv1[0], acc1[0]);
      acc0[1] = fmaf(w0, xv0[1], acc0[1]); acc1[1] = fmaf(w1, xv1[1], acc1[1]);
      acc0[2] = fmaf(w0, xv0[2], acc0[2]); acc1[2] = fmaf(w1, xv1[2], acc1[2]);
      acc0[3] = fmaf(w0, xv0[3], acc0[3]); acc1[3] = fmaf(w1, xv1[3], acc1[3]);
    }
    {
      f32x4 xv = *(const f32x4*)(xc + (size_t)24 * B_D);
      float w = scores[p * 25 + 24];
      acc0[0] = fmaf(w, xv[0], acc0[0]); acc0[1] = fmaf(w, xv[1], acc0[1]);
      acc0[2] = fmaf(w, xv[2], acc0[2]); acc0[3] = fmaf(w, xv[3], acc0[3]);
    }
    acc0[0] += acc1[0]; acc0[1] += acc1[1]; acc0[2] += acc1[2]; acc0[3] += acc1[3];
    *(f32x4*)&part[p][d4] = acc0;
  }
  __syncthreads();
  if (tid < B_D) {
    float Z = (red[4] + red[5]) + (red[6] + red[7]);
    float s = 0.f;
    #pragma unroll
    for (int p = 0; p < 8; ++p) s += part[p][tid];
    out[(size_t)b * B_D + tid] = s / Z;
  }
}

extern "C" void kernel_launch(void* const* d_in, const int* in_sizes, int n_in,
                              void* d_out, int out_size, void* d_ws, size_t ws_size,
                              hipStream_t stream) {
  const float* x    = (const float*)d_in[0];
  const float* cand = (const float*)d_in[1];
  const void*  mask = d_in[2];
  const float* W1   = (const float*)d_in[3];
  const float* b1   = (const float*)d_in[4];
  const float* a    = (const float*)d_in[5];
  const float* W2   = (const float*)d_in[6];
  const float* b2   = (const float*)d_in[7];
  float* out = (float*)d_out;
  const int B = in_sizes[1] / B_D;   // candidate is [B,128]
  ta_fused<<<B, 256, 0, stream>>>(x, cand, mask, W1, b1, a, W2, b2, out);
}

// Round 17
// 318.879 us; speedup vs baseline: 1.2043x; 1.2043x over previous
//
#include <hip/hip_runtime.h>
#include <hip/hip_bf16.h>

typedef __attribute__((ext_vector_type(8))) short short8;
typedef __attribute__((ext_vector_type(4))) float f32x4;

#define B_T 200
#define B_D 128
#define ALD 136   // padded bf16 leading dim for staged x tiles (row = 272 B)

static __device__ __forceinline__ short f2bf(float f) {
  // round-to-nearest-even f32 -> bf16 (inputs are finite)
  unsigned u = __builtin_bit_cast(unsigned, f);
  u += 0x7fffu + ((u >> 16) & 1u);
  return (short)(u >> 16);
}
static __device__ __forceinline__ short8 cvt8(f32x4 a, f32x4 b) {
  short8 t;
  t[0] = f2bf(a[0]); t[1] = f2bf(a[1]); t[2] = f2bf(a[2]); t[3] = f2bf(a[3]);
  t[4] = f2bf(b[0]); t[5] = f2bf(b[1]); t[6] = f2bf(b[2]); t[7] = f2bf(b[3]);
  return t;
}

// 256 threads / 4 waves. Wb in REGISTERS (2 nt columns/wave = 32 VGPRs);
// x tiles staged in LDS (21.5 KB total).
// waves_per_eu(4, 8): min=4 -> 128-reg/wave budget (R15-proven, no spill;
// R16's (5,5) drove a 102-unified budget -> VGPR=48 + 538 MB scratch spill);
// max=8 -> HW may pack 5-6 waves/EU if allocation lands <=102/85.
__global__ __launch_bounds__(256)
__attribute__((amdgpu_waves_per_eu(4, 8)))
void ta_fused(const float* __restrict__ x,      // [B,T,D]
              const float* __restrict__ cand,   // [B,D]
              const void*  __restrict__ maskp,  // [B,T] int32 or 1-byte bool
              const float* __restrict__ W1,     // [384,128]
              const float* __restrict__ b1,     // [128]
              const float* __restrict__ ap,     // [1]
              const float* __restrict__ W2,     // [128]
              const float* __restrict__ b2p,    // [1] (unused: softmax shift-invariant)
              float* __restrict__ out)          // [B,D]
{
  __shared__ __align__(16) short a_lds[3][16 * ALD];  // 12.75 KB: x tiles bf16
  __shared__ float sp[4][208];                        // per-wave score partials
  __shared__ float scores[208];
  __shared__ float part[8][B_D];                      // phase-C partials
  __shared__ float red[8];

  const int b    = blockIdx.x;
  const int tid  = threadIdx.x;
  const int lane = tid & 63;
  const int wv   = tid >> 6;      // 0..3
  const int l15  = lane & 15;
  const int g    = lane >> 4;     // 0..3

  // ---- mask dtype probe (same 512B on every wave -> block-consistent)
  int flag1b;
  {
    const unsigned char* mb = (const unsigned char*)maskp;
    unsigned long long v8 = *(const unsigned long long*)(mb + lane * 8);
    flag1b = __any((v8 & 0xFFFFFF00FFFFFF00ull) != 0ull);
  }
  bool mk = false;
  if (tid < B_T) {
    if (flag1b) mk = ((const unsigned char*)maskp)[(size_t)b * B_T + tid] != 0;
    else        mk = ((const int*)maskp)[(size_t)b * B_T + tid] != 0;
  }

  // ---- stage tiles 0 and 1 (loads issued before the Wb build -> overlap)
#define STAGE(MT, BUF) do {                                                   \
    int srow_ = (MT) * 16 + (tid >> 4);                                       \
    if (srow_ > B_T - 1) srow_ = B_T - 1;                                     \
    const float* xp_ = x + ((size_t)b * B_T + srow_) * B_D + (tid & 15) * 8;  \
    f32x4 v0_ = *(const f32x4*)xp_;                                           \
    f32x4 v1_ = *(const f32x4*)(xp_ + 4);                                     \
    *(short8*)&a_lds[BUF][(tid >> 4) * ALD + (tid & 15) * 8] = cvt8(v0_, v1_);\
  } while (0)

  STAGE(0, 0);
  STAGE(1, 1);

  // ---- phase 1 (register-resident, no LDS, no barrier):
  // B-frags for nt=2wv (j0=32wv+l15) and nt=2wv+1 (j1=j0+16):
  // B0[ks] elem e = bf16(W1a[k][j] + c[k]*W1c[k][j]), k = ks*32+g*8+e.
  const float* cb = cand + (size_t)b * B_D;
  const int j0 = wv * 32 + l15, j1 = j0 + 16;
  short8 B0[4], B1[4];
  #pragma unroll
  for (int ks = 0; ks < 4; ++ks) {
    short8 t0, t1;
    #pragma unroll
    for (int e = 0; e < 8; ++e) {
      const int k = ks * 32 + g * 8 + e;
      float c = cb[k];
      t0[e] = f2bf(fmaf(c, W1[(size_t)(256 + k) * B_D + j0], W1[(size_t)k * B_D + j0]));
      t1[e] = f2bf(fmaf(c, W1[(size_t)(256 + k) * B_D + j1], W1[(size_t)k * B_D + j1]));
    }
    B0[ks] = t0; B1[ks] = t1;
  }
  // beta for j0/j1: lane (g) sums k in [g*32,g*32+32), then reduce over g.
  float betaL0, betaL1;
  {
    float s0 = 0.f, s1 = 0.f;
    #pragma unroll 8
    for (int kk = 0; kk < 32; ++kk) {
      const int k = g * 32 + kk;
      float c = cb[k];
      s0 = fmaf(c, W1[(size_t)(B_D + k) * B_D + j0], s0);
      s1 = fmaf(c, W1[(size_t)(B_D + k) * B_D + j1], s1);
    }
    s0 += __shfl_xor(s0, 16, 64); s0 += __shfl_xor(s0, 32, 64);
    s1 += __shfl_xor(s1, 16, 64); s1 += __shfl_xor(s1, 32, 64);
    betaL0 = s0 + b1[j0];
    betaL1 = s1 + b1[j1];
  }
  const float w2L0 = W2[j0], w2L1 = W2[j1];
  const float alpha = ap[0];
  __syncthreads();   // tiles 0,1 staged

  // ---- phase A: 13 tiles, triple-buffered (prefetch distance 2).
  for (int mt = 0; mt < 13; ++mt) {
    const int buf = mt % 3;
    if (mt + 2 < 13) STAGE(mt + 2, (mt + 2) % 3);
    f32x4 acc0 = {0.f, 0.f, 0.f, 0.f}, acc1 = {0.f, 0.f, 0.f, 0.f};
    #pragma unroll
    for (int ks = 0; ks < 4; ++ks) {
      short8 a = *(const short8*)&a_lds[buf][l15 * ALD + ks * 32 + g * 8];
      acc0 = __builtin_amdgcn_mfma_f32_16x16x32_bf16(a, B0[ks], acc0, 0, 0, 0);
      acc1 = __builtin_amdgcn_mfma_f32_16x16x32_bf16(a, B1[ks], acc1, 0, 0, 0);
    }
    // epilogue: PReLU + W2 over this wave's 32 j, reduce over l15
    #pragma unroll
    for (int r = 0; r < 4; ++r) {
      float h0 = acc0[r] + betaL0; h0 = (h0 >= 0.f) ? h0 : alpha * h0;
      float h1 = acc1[r] + betaL1; h1 = (h1 >= 0.f) ? h1 : alpha * h1;
      float v = h0 * w2L0 + h1 * w2L1;
      v += __shfl_xor(v, 1, 16); v += __shfl_xor(v, 2, 16);
      v += __shfl_xor(v, 4, 16); v += __shfl_xor(v, 8, 16);
      if (l15 == 0) sp[wv][mt * 16 + g * 4 + r] = v;   // C row = g*4+r
    }
    __syncthreads();   // releases buf for overwrite; commits staged tile
  }
#undef STAGE

  // ---- phase B: sum wave partials, masked softmax; scores <- UNNORMALIZED e.
  {
    float s = -INFINITY;
    if (tid < B_T && mk) s = (sp[0][tid] + sp[1][tid]) + (sp[2][tid] + sp[3][tid]);
    float v = s;
    #pragma unroll
    for (int m = 32; m >= 1; m >>= 1) v = fmaxf(v, __shfl_xor(v, m, 64));
    if (lane == 0) red[wv] = v;
    __syncthreads();
    float mx = fmaxf(fmaxf(red[0], red[1]), fmaxf(red[2], red[3]));
    float e = (tid < B_T && mk) ? __expf(s - mx) : 0.f;
    float sv = e;
    #pragma unroll
    for (int m = 32; m >= 1; m >>= 1) sv += __shfl_xor(sv, m, 64);
    if (lane == 0) red[4 + wv] = sv;
    if (tid < 208) scores[tid] = e;   // tid in [200,208): e==0
    __syncthreads();
  }

  // ---- phase C: part[p][:] = sum_{t in p-slice} e[t]*x[t,:] (L2/L3-hot).
  {
    const int d4 = (tid & 31) << 2;
    const int p  = tid >> 5;            // 0..7, t in [25p, 25p+25)
    const float* xc = x + ((size_t)b * B_T + p * 25) * B_D + d4;
    f32x4 acc0 = {0.f, 0.f, 0.f, 0.f}, acc1 = {0.f, 0.f, 0.f, 0.f};
    #pragma unroll
    for (int t = 0; t < 24; t += 2) {
      f32x4 xv0 = *(const f32x4*)(xc + (size_t)t * B_D);
      f32x4 xv1 = *(const f32x4*)(xc + (size_t)(t + 1) * B_D);
      float w0 = scores[p * 25 + t];
      float w1 = scores[p * 25 + t + 1];
      acc0[0] = fmaf(w0, xv0[0], acc0[0]); acc1[0] = fmaf(w1, xv1[0], acc1[0]);
      acc0[1] = fmaf(w0, xv0[1], acc0[1]); acc1[1] = fmaf(w1, xv1[1], acc1[1]);
      acc0[2] = fmaf(w0, xv0[2], acc0[2]); acc1[2] = fmaf(w1, xv1[2], acc1[2]);
      acc0[3] = fmaf(w0, xv0[3], acc0[3]); acc1[3] = fmaf(w1, xv1[3], acc1[3]);
    }
    {
      f32x4 xv = *(const f32x4*)(xc + (size_t)24 * B_D);
      float w = scores[p * 25 + 24];
      acc0[0] = fmaf(w, xv[0], acc0[0]); acc0[1] = fmaf(w, xv[1], acc0[1]);
      acc0[2] = fmaf(w, xv[2], acc0[2]); acc0[3] = fmaf(w, xv[3], acc0[3]);
    }
    acc0[0] += acc1[0]; acc0[1] += acc1[1]; acc0[2] += acc1[2]; acc0[3] += acc1[3];
    *(f32x4*)&part[p][d4] = acc0;
  }
  __syncthreads();
  if (tid < B_D) {
    float Z = (red[4] + red[5]) + (red[6] + red[7]);
    float s = 0.f;
    #pragma unroll
    for (int p = 0; p < 8; ++p) s += part[p][tid];
    out[(size_t)b * B_D + tid] = s / Z;
  }
}

extern "C" void kernel_launch(void* const* d_in, const int* in_sizes, int n_in,
                              void* d_out, int out_size, void* d_ws, size_t ws_size,
                              hipStream_t stream) {
  const float* x    = (const float*)d_in[0];
  const float* cand = (const float*)d_in[1];
  const void*  mask = d_in[2];
  const float* W1   = (const float*)d_in[3];
  const float* b1   = (const float*)d_in[4];
  const float* a    = (const float*)d_in[5];
  const float* W2   = (const float*)d_in[6];
  const float* b2   = (const float*)d_in[7];
  float* out = (float*)d_out;
  const int B = in_sizes[1] / B_D;   // candidate is [B,128]
  ta_fused<<<B, 256, 0, stream>>>(x, cand, mask, W1, b1, a, W2, b2, out);
}

// Round 18
// 317.091 us; speedup vs baseline: 1.2111x; 1.0056x over previous
//
#include <hip/hip_runtime.h>
#include <hip/hip_bf16.h>

typedef __attribute__((ext_vector_type(8))) short short8;
typedef __attribute__((ext_vector_type(4))) float f32x4;

#define B_T 200
#define B_D 128

static __device__ __forceinline__ short f2bf(float f) {
  // round-to-nearest-even f32 -> bf16 (inputs are finite)
  unsigned u = __builtin_bit_cast(unsigned, f);
  u += 0x7fffu + ((u >> 16) & 1u);
  return (short)(u >> 16);
}
static __device__ __forceinline__ short8 cvt8(f32x4 a, f32x4 b) {
  short8 t;
  t[0] = f2bf(a[0]); t[1] = f2bf(a[1]); t[2] = f2bf(a[2]); t[3] = f2bf(a[3]);
  t[4] = f2bf(b[0]); t[5] = f2bf(b[1]); t[6] = f2bf(b[2]); t[7] = f2bf(b[3]);
  return t;
}

// 256 threads / 4 waves. Wb in REGISTERS (2 nt columns/wave = 32 VGPRs);
// x tiles staged in LDS with XOR-swizzled octet layout (20 KB total).
// waves_per_eu(4,4): the ONLY setting that never spilled (R15). The backend
// sizes the register budget for the RANGE MAX: (5,5)->48 arch VGPR + spill
// (R16), (4,8)->64 + spill (R17). min=max=4 -> 128-reg budget, demand ~105.
__global__ __launch_bounds__(256)
__attribute__((amdgpu_waves_per_eu(4, 4)))
void ta_fused(const float* __restrict__ x,      // [B,T,D]
              const float* __restrict__ cand,   // [B,D]
              const void*  __restrict__ maskp,  // [B,T] int32 or 1-byte bool
              const float* __restrict__ W1,     // [384,128]
              const float* __restrict__ b1,     // [128]
              const float* __restrict__ ap,     // [1]
              const float* __restrict__ W2,     // [128]
              const float* __restrict__ b2p,    // [1] (unused: softmax shift-invariant)
              float* __restrict__ out)          // [B,D]
{
  // a_lds layout: 16B octet o (= k/8, 0..15) of row r at shorts
  // [r*128 + (o ^ (r&7))*8]. Writes (4 rows x 16 octets/wave) and reads
  // (16 rows x 4 octets/wave) both land at the 256-dword/32-bank floor.
  __shared__ __align__(16) short a_lds[3][16 * B_D];  // 12 KB: x tiles bf16
  __shared__ float sp[4][208];                        // per-wave score partials
  __shared__ float scores[208];
  __shared__ float part[8][B_D];                      // phase-C partials
  __shared__ float red[8];

  const int b    = blockIdx.x;
  const int tid  = threadIdx.x;
  const int lane = tid & 63;
  const int wv   = tid >> 6;      // 0..3
  const int l15  = lane & 15;
  const int g    = lane >> 4;     // 0..3

  // ---- mask dtype probe (same 512B on every wave -> block-consistent)
  int flag1b;
  {
    const unsigned char* mb = (const unsigned char*)maskp;
    unsigned long long v8 = *(const unsigned long long*)(mb + lane * 8);
    flag1b = __any((v8 & 0xFFFFFF00FFFFFF00ull) != 0ull);
  }
  bool mk = false;
  if (tid < B_T) {
    if (flag1b) mk = ((const unsigned char*)maskp)[(size_t)b * B_T + tid] != 0;
    else        mk = ((const int*)maskp)[(size_t)b * B_T + tid] != 0;
  }

  // ---- stage tiles 0 and 1 (loads issued before the Wb build -> overlap)
#define STAGE(MT, BUF) do {                                                   \
    const int r_ = tid >> 4, c_ = tid & 15;                                   \
    int srow_ = (MT) * 16 + r_;                                               \
    if (srow_ > B_T - 1) srow_ = B_T - 1;                                     \
    const float* xp_ = x + ((size_t)b * B_T + srow_) * B_D + c_ * 8;          \
    f32x4 v0_ = *(const f32x4*)xp_;                                           \
    f32x4 v1_ = *(const f32x4*)(xp_ + 4);                                     \
    *(short8*)&a_lds[BUF][r_ * B_D + ((c_ ^ (r_ & 7)) << 3)] = cvt8(v0_, v1_);\
  } while (0)

  STAGE(0, 0);
  STAGE(1, 1);

  // ---- phase 1 (register-resident, no LDS, no barrier):
  // B-frags for nt=2wv (j0=32wv+l15) and nt=2wv+1 (j1=j0+16).
  const float* cb = cand + (size_t)b * B_D;
  const int j0 = wv * 32 + l15, j1 = j0 + 16;
  short8 B0[4], B1[4];
  #pragma unroll
  for (int ks = 0; ks < 4; ++ks) {
    short8 t0, t1;
    #pragma unroll
    for (int e = 0; e < 8; ++e) {
      const int k = ks * 32 + g * 8 + e;
      float c = cb[k];
      t0[e] = f2bf(fmaf(c, W1[(size_t)(256 + k) * B_D + j0], W1[(size_t)k * B_D + j0]));
      t1[e] = f2bf(fmaf(c, W1[(size_t)(256 + k) * B_D + j1], W1[(size_t)k * B_D + j1]));
    }
    B0[ks] = t0; B1[ks] = t1;
  }
  // beta for j0/j1: lane (g) sums k in [g*32,g*32+32), then reduce over g.
  float betaL0, betaL1;
  {
    float s0 = 0.f, s1 = 0.f;
    #pragma unroll 8
    for (int kk = 0; kk < 32; ++kk) {
      const int k = g * 32 + kk;
      float c = cb[k];
      s0 = fmaf(c, W1[(size_t)(B_D + k) * B_D + j0], s0);
      s1 = fmaf(c, W1[(size_t)(B_D + k) * B_D + j1], s1);
    }
    s0 += __shfl_xor(s0, 16, 64); s0 += __shfl_xor(s0, 32, 64);
    s1 += __shfl_xor(s1, 16, 64); s1 += __shfl_xor(s1, 32, 64);
    betaL0 = s0 + b1[j0];
    betaL1 = s1 + b1[j1];
  }
  const float w2L0 = W2[j0], w2L1 = W2[j1];
  const float alpha = ap[0];
  __syncthreads();   // tiles 0,1 staged

  // ---- phase A: 13 tiles, triple-buffered (prefetch distance 2).
  for (int mt = 0; mt < 13; ++mt) {
    const int buf = mt % 3;
    if (mt + 2 < 13) STAGE(mt + 2, (mt + 2) % 3);
    f32x4 acc0 = {0.f, 0.f, 0.f, 0.f}, acc1 = {0.f, 0.f, 0.f, 0.f};
    #pragma unroll
    for (int ks = 0; ks < 4; ++ks) {
      // A-frag (row=l15, octet o=ks*4+g) at swizzled offset
      short8 a = *(const short8*)
          &a_lds[buf][l15 * B_D + (((ks * 4 + g) ^ (l15 & 7)) << 3)];
      acc0 = __builtin_amdgcn_mfma_f32_16x16x32_bf16(a, B0[ks], acc0, 0, 0, 0);
      acc1 = __builtin_amdgcn_mfma_f32_16x16x32_bf16(a, B1[ks], acc1, 0, 0, 0);
    }
    // epilogue: PReLU + W2 over this wave's 32 j, reduce over l15
    #pragma unroll
    for (int r = 0; r < 4; ++r) {
      float h0 = acc0[r] + betaL0; h0 = (h0 >= 0.f) ? h0 : alpha * h0;
      float h1 = acc1[r] + betaL1; h1 = (h1 >= 0.f) ? h1 : alpha * h1;
      float v = h0 * w2L0 + h1 * w2L1;
      v += __shfl_xor(v, 1, 16); v += __shfl_xor(v, 2, 16);
      v += __shfl_xor(v, 4, 16); v += __shfl_xor(v, 8, 16);
      if (l15 == 0) sp[wv][mt * 16 + g * 4 + r] = v;   // C row = g*4+r
    }
    __syncthreads();   // releases buf for overwrite; commits staged tile
  }
#undef STAGE

  // ---- phase B: sum wave partials, masked softmax; scores <- UNNORMALIZED e.
  {
    float s = -INFINITY;
    if (tid < B_T && mk) s = (sp[0][tid] + sp[1][tid]) + (sp[2][tid] + sp[3][tid]);
    float v = s;
    #pragma unroll
    for (int m = 32; m >= 1; m >>= 1) v = fmaxf(v, __shfl_xor(v, m, 64));
    if (lane == 0) red[wv] = v;
    __syncthreads();
    float mx = fmaxf(fmaxf(red[0], red[1]), fmaxf(red[2], red[3]));
    float e = (tid < B_T && mk) ? __expf(s - mx) : 0.f;
    float sv = e;
    #pragma unroll
    for (int m = 32; m >= 1; m >>= 1) sv += __shfl_xor(sv, m, 64);
    if (lane == 0) red[4 + wv] = sv;
    if (tid < 208) scores[tid] = e;   // tid in [200,208): e==0
    __syncthreads();
  }

  // ---- phase C: part[p][:] = sum_{t in p-slice} e[t]*x[t,:] (L2/L3-hot).
  {
    const int d4 = (tid & 31) << 2;
    const int p  = tid >> 5;            // 0..7, t in [25p, 25p+25)
    const float* xc = x + ((size_t)b * B_T + p * 25) * B_D + d4;
    f32x4 acc0 = {0.f, 0.f, 0.f, 0.f}, acc1 = {0.f, 0.f, 0.f, 0.f};
    #pragma unroll
    for (int t = 0; t < 24; t += 2) {
      f32x4 xv0 = *(const f32x4*)(xc + (size_t)t * B_D);
      f32x4 xv1 = *(const f32x4*)(xc + (size_t)(t + 1) * B_D);
      float w0 = scores[p * 25 + t];
      float w1 = scores[p * 25 + t + 1];
      acc0[0] = fmaf(w0, xv0[0], acc0[0]); acc1[0] = fmaf(w1, xv1[0], acc1[0]);
      acc0[1] = fmaf(w0, xv0[1], acc0[1]); acc1[1] = fmaf(w1, xv1[1], acc1[1]);
      acc0[2] = fmaf(w0, xv0[2], acc0[2]); acc1[2] = fmaf(w1, xv1[2], acc1[2]);
      acc0[3] = fmaf(w0, xv0[3], acc0[3]); acc1[3] = fmaf(w1, xv1[3], acc1[3]);
    }
    {
      f32x4 xv = *(const f32x4*)(xc + (size_t)24 * B_D);
      float w = scores[p * 25 + 24];
      acc0[0] = fmaf(w, xv[0], acc0[0]); acc0[1] = fmaf(w, xv[1], acc0[1]);
      acc0[2] = fmaf(w, xv[2], acc0[2]); acc0[3] = fmaf(w, xv[3], acc0[3]);
    }
    acc0[0] += acc1[0]; acc0[1] += acc1[1]; acc0[2] += acc1[2]; acc0[3] += acc1[3];
    *(f32x4*)&part[p][d4] = acc0;
  }
  __syncthreads();
  if (tid < B_D) {
    float Z = (red[4] + red[5]) + (red[6] + red[7]);
    float s = 0.f;
    #pragma unroll
    for (int p = 0; p < 8; ++p) s += part[p][tid];
    out[(size_t)b * B_D + tid] = s / Z;
  }
}

extern "C" void kernel_launch(void* const* d_in, const int* in_sizes, int n_in,
                              void* d_out, int out_size, void* d_ws, size_t ws_size,
                              hipStream_t stream) {
  const float* x    = (const float*)d_in[0];
  const float* cand = (const float*)d_in[1];
  const void*  mask = d_in[2];
  const float* W1   = (const float*)d_in[3];
  const float* b1   = (const float*)d_in[4];
  const float* a    = (const float*)d_in[5];
  const float* W2   = (const float*)d_in[6];
  const float* b2   = (const float*)d_in[7];
  float* out = (float*)d_out;
  const int B = in_sizes[1] / B_D;   // candidate is [B,128]
  ta_fused<<<B, 256, 0, stream>>>(x, cand, mask, W1, b1, a, W2, b2, out);
}